// Round 3
// baseline (231.438 us; speedup 1.0000x reference)
//
#include <hip/hip_runtime.h>
#include <cstdint>
#include <cmath>

#define B_ 128
#define P_ 8732
#define M_ 16
#define NT 1024
#define NW (NT / 64)   // 16 waves == M_ objects

__device__ __forceinline__ float softplusf(float x) {
    // logaddexp(0, x) = max(x,0) + log1p(exp(-|x|))
    return fmaxf(x, 0.0f) + log1pf(expf(-fabsf(x)));
}

__device__ __forceinline__ float wred_sum_f(float v) {
#pragma unroll
    for (int o = 32; o > 0; o >>= 1) v += __shfl_down(v, o, 64);
    return v;
}
__device__ __forceinline__ int wred_sum_i(int v) {
#pragma unroll
    for (int o = 32; o > 0; o >>= 1) v += __shfl_down(v, o, 64);
    return v;
}

__global__ __launch_bounds__(NT, 4) void mbox_row_kernel(
    const float* __restrict__ plocs,   // (B,P,4)
    const float* __restrict__ pscores, // (B,P,3)
    const float* __restrict__ boxes,   // (B,M,4) xyxy
    const int*   __restrict__ labels,  // (B,M)
    const float* __restrict__ priors,  // (P,4) cxcy
    float* __restrict__ out,           // [total, conf, loc, npos x 128]
    unsigned int* __restrict__ g_cnt,  // ws: zeroed counter
    float* __restrict__ g_conf,        // ws
    float* __restrict__ g_loc,         // ws
    int*   __restrict__ g_np)          // ws
{
    __shared__ float s_vals[P_];          // ov_prior, then bce_neg
    __shared__ unsigned char s_obj[P_];   // obj_prior
    __shared__ float s_boxes[M_ * 4];
    __shared__ float s_area[M_];
    __shared__ int   s_labels[M_];
    __shared__ int   s_prior_obj[M_];
    __shared__ float s_pf[2 * NW];        // partial sums (conf, loc)
    __shared__ int   s_pi[NW];            // partial n_pos
    __shared__ float s_scal[2];
    __shared__ int   s_npos;
    __shared__ unsigned int s_hist[256];
    __shared__ unsigned int s_prefix;
    __shared__ int s_remaining;

    const int b = blockIdx.x;
    const int tid = threadIdx.x;
    const int lane = tid & 63;
    const int wid = tid >> 6;

    if (tid < M_ * 4) s_boxes[tid] = boxes[b * M_ * 4 + tid];
    if (tid >= 64 && tid < 64 + M_) s_labels[tid - 64] = labels[b * M_ + (tid - 64)];
    __syncthreads();
    if (tid < M_) {
        float x0 = s_boxes[tid*4+0], y0 = s_boxes[tid*4+1];
        float x1 = s_boxes[tid*4+2], y1 = s_boxes[tid*4+3];
        s_area[tid] = (x1 - x0) * (y1 - y0);
    }
    __syncthreads();

    // ---- Phase A: per-prior best object (argmax over m, first-max).
    for (int p = tid; p < P_; p += NT) {
        float4 pr = ((const float4*)priors)[p];
        float px0 = pr.x - pr.z * 0.5f;
        float py0 = pr.y - pr.w * 0.5f;
        float px1 = pr.x + pr.z * 0.5f;
        float py1 = pr.y + pr.w * 0.5f;
        float parea = pr.z * pr.w;
        float bestv = -1.0f; int besti = 0;
#pragma unroll
        for (int m = 0; m < M_; ++m) {
            float ltx = fmaxf(s_boxes[m*4+0], px0);
            float lty = fmaxf(s_boxes[m*4+1], py0);
            float rbx = fminf(s_boxes[m*4+2], px1);
            float rby = fminf(s_boxes[m*4+3], py1);
            float wx = fmaxf(rbx - ltx, 0.0f);
            float wy = fmaxf(rby - lty, 0.0f);
            float inter = wx * wy;
            float ov = inter / (s_area[m] + parea - inter);
            if (ov > bestv) { bestv = ov; besti = m; }       // first-max over m
        }
        s_vals[p] = bestv;
        s_obj[p]  = (unsigned char)besti;
    }

    // ---- Phase B: per-object best prior — one WAVE per object, recompute IoU
    {
        const int m = wid;               // NW == M_
        float bx0 = s_boxes[m*4+0], by0 = s_boxes[m*4+1];
        float bx1 = s_boxes[m*4+2], by1 = s_boxes[m*4+3];
        float marea = s_area[m];
        float bv = -1.0f; int bi = 0x7FFFFFFF;
        for (int p = lane; p < P_; p += 64) {
            float4 pr = ((const float4*)priors)[p];
            float px0 = pr.x - pr.z * 0.5f;
            float py0 = pr.y - pr.w * 0.5f;
            float px1 = pr.x + pr.z * 0.5f;
            float py1 = pr.y + pr.w * 0.5f;
            float ltx = fmaxf(bx0, px0);
            float lty = fmaxf(by0, py0);
            float rbx = fminf(bx1, px1);
            float rby = fminf(by1, py1);
            float wx = fmaxf(rbx - ltx, 0.0f);
            float wy = fmaxf(rby - lty, 0.0f);
            float inter = wx * wy;
            float ov = inter / (marea + pr.z * pr.w - inter);
            if (ov > bv) { bv = ov; bi = p; }   // first-max (p ascending per lane)
        }
#pragma unroll
        for (int o = 32; o > 0; o >>= 1) {
            float v2 = __shfl_down(bv, o, 64);
            int   i2 = __shfl_down(bi, o, 64);
            if (v2 > bv || (v2 == bv && i2 < bi)) { bv = v2; bi = i2; }
        }
        if (lane == 0) s_prior_obj[m] = bi;
    }
    __syncthreads();

    // ---- Phase C: fixup scatter (serial, last m wins on duplicate priors)
    if (tid == 0) {
        for (int m = 0; m < M_; ++m) {
            int idx = s_prior_obj[m];
            s_obj[idx]  = (unsigned char)m;
            s_vals[idx] = 1.0f;
        }
    }
    __syncthreads();

    // ---- Phase D: labels, BCE, L1 on positives; write bce_neg in place
    int   n_pos = 0;
    float conf_pos = 0.0f;
    float loc_sum = 0.0f;
    for (int p = tid; p < P_; p += NT) {
        float ovp = s_vals[p];
        int obj = s_obj[p];
        int lab = (ovp < 0.5f) ? 0 : s_labels[obj];
        const float* sc = pscores + ((size_t)b * P_ + p) * 3;
        float x0 = sc[0], x1 = sc[1], x2 = sc[2];
        float t0 = (lab == 0) ? 1.0f : 0.0f;
        float t1 = (lab == 1 || lab == 3) ? 1.0f : 0.0f;
        float t2 = (lab == 2 || lab == 3) ? 1.0f : 0.0f;
        float bce = (softplusf(x0) - x0*t0) + (softplusf(x1) - x1*t1) + (softplusf(x2) - x2*t2);
        bool pos = lab > 0;
        if (pos) {
            n_pos++;
            conf_pos += bce;
            float4 pr = ((const float4*)priors)[p];
            float bx0 = s_boxes[obj*4+0], by0 = s_boxes[obj*4+1];
            float bx1 = s_boxes[obj*4+2], by1 = s_boxes[obj*4+3];
            float cx = (bx0 + bx1) * 0.5f, cy = (by0 + by1) * 0.5f;
            float w = bx1 - bx0, h = by1 - by0;
            float g0 = (cx - pr.x) / (pr.z * 0.1f);
            float g1 = (cy - pr.y) / (pr.w * 0.1f);
            float g2 = logf(w / pr.z) * 5.0f;
            float g3 = logf(h / pr.w) * 5.0f;
            float4 pl = ((const float4*)plocs)[(size_t)b * P_ + p];
            loc_sum += fabsf(pl.x - g0) + fabsf(pl.y - g1) + fabsf(pl.z - g2) + fabsf(pl.w - g3);
        }
        s_vals[p] = pos ? 0.0f : bce;   // conf_neg (zeros at positives)
    }

    // ---- reduce n_pos, conf_pos, loc_sum (wave shuffle + cross-wave)
    {
        float cp = wred_sum_f(conf_pos);
        float ls = wred_sum_f(loc_sum);
        int   np = wred_sum_i(n_pos);
        if (lane == 0) { s_pf[wid] = cp; s_pf[NW + wid] = ls; s_pi[wid] = np; }
    }
    __syncthreads();
    if (tid == 0) {
        float cp = 0.0f, ls = 0.0f; int np = 0;
#pragma unroll
        for (int w = 0; w < NW; ++w) { cp += s_pf[w]; ls += s_pf[NW + w]; np += s_pi[w]; }
        s_scal[0] = cp; s_scal[1] = ls; s_npos = np;
    }
    __syncthreads();
    const int npos_row = s_npos;

    // ---- Phase E: hard-negative mining = exact top-k sum via radix select
    int k = 3 * npos_row;
    if (k > P_) k = P_;
    float hard_sum = 0.0f;
    if (k > 0) {
        if (tid == 0) { s_prefix = 0u; s_remaining = k; }
        if (tid < 256) s_hist[tid] = 0u;
        __syncthreads();
        for (int shift = 24; shift >= 0; shift -= 8) {
            unsigned int prefix = s_prefix;
            unsigned int mask_hi = (shift == 24) ? 0u : (0xFFFFFFFFu << (shift + 8));
            for (int p = tid; p < P_; p += NT) {
                unsigned int u = __float_as_uint(s_vals[p]);
                if ((u & mask_hi) == prefix)
                    atomicAdd(&s_hist[(u >> shift) & 255u], 1u);
            }
            __syncthreads();
            if (tid == 0) {
                int rem = s_remaining;
                unsigned int cum = 0;
                for (int bin = 255; bin >= 0; --bin) {
                    unsigned int c = s_hist[bin];
                    if (cum + c >= (unsigned int)rem) {
                        s_prefix = prefix | ((unsigned int)bin << shift);
                        s_remaining = rem - (int)cum;
                        break;
                    }
                    cum += c;
                }
            }
            __syncthreads();
            if (tid < 256) s_hist[tid] = 0u;   // clear for next pass
            __syncthreads();
        }
        unsigned int tbits = s_prefix;   // k-th largest bit pattern (exact)
        float tval = __uint_as_float(tbits);
        float lsum = 0.0f; int lcnt = 0;
        for (int p = tid; p < P_; p += NT) {
            float v = s_vals[p];
            if (__float_as_uint(v) > tbits) { lsum += v; lcnt++; }
        }
        lsum = wred_sum_f(lsum);
        lcnt = wred_sum_i(lcnt);
        if (lane == 0) { s_pf[wid] = lsum; s_pi[wid] = lcnt; }
        __syncthreads();
        if (tid == 0) {
            float sv = 0.0f; int sc2 = 0;
#pragma unroll
            for (int w = 0; w < NW; ++w) { sv += s_pf[w]; sc2 += s_pi[w]; }
            hard_sum = sv + (float)(k - sc2) * tval;
        }
    }

    // ---- finalize: per-row output + last-block global reduction
    if (tid == 0) {
        float conf_row = s_scal[0] + hard_sum;
        float loc_row  = s_scal[1];
        out[3 + b] = (float)npos_row;
        atomicAdd(g_conf, conf_row);
        atomicAdd(g_loc,  loc_row);
        atomicAdd(g_np,   npos_row);
        __threadfence();
        unsigned int done = atomicAdd(g_cnt, 1u);
        if (done == B_ - 1) {
            float ct = atomicAdd(g_conf, 0.0f);  // read at coherent point
            float lt = atomicAdd(g_loc,  0.0f);
            int   np = atomicAdd(g_np,   0);
            float npt = (float)np;
            float conf_loss = ct / (1e-10f + npt);
            float loc_loss = (np > 0) ? lt / (4.0f * fmaxf(npt, 1.0f)) : 0.0f;
            out[0] = conf_loss + loc_loss;   // ALPHA = 1
            out[1] = conf_loss;
            out[2] = loc_loss;
        }
    }
}

extern "C" void kernel_launch(void* const* d_in, const int* in_sizes, int n_in,
                              void* d_out, int out_size, void* d_ws, size_t ws_size,
                              hipStream_t stream) {
    const float* plocs   = (const float*)d_in[0];  // (B,P,4)
    const float* pscores = (const float*)d_in[1];  // (B,P,3)
    const float* boxes   = (const float*)d_in[2];  // (B,M,4)
    const int*   labels  = (const int*)  d_in[3];  // (B,M)
    const float* priors  = (const float*)d_in[4];  // (P,4)
    float* out = (float*)d_out;

    unsigned int* g_cnt  = (unsigned int*)d_ws;
    float*        g_conf = (float*)((char*)d_ws + 4);
    float*        g_loc  = (float*)((char*)d_ws + 8);
    int*          g_np   = (int*)  ((char*)d_ws + 12);

    hipMemsetAsync(d_ws, 0, 16, stream);   // zero counter + accumulators
    mbox_row_kernel<<<B_, NT, 0, stream>>>(plocs, pscores, boxes, labels, priors,
                                           out, g_cnt, g_conf, g_loc, g_np);
}

// Round 4
// 174.547 us; speedup vs baseline: 1.3259x; 1.3259x over previous
//
#include <hip/hip_runtime.h>
#include <cstdint>
#include <cmath>

#define B_ 128
#define P_ 8732
#define M_ 16
#define NT 1024
#define NW (NT / 64)
#define NP9 9   // ceil(P_/NT)

__device__ __forceinline__ float softplusf(float x) {
    // logaddexp(0, x) = max(x,0) + log1p(exp(-|x|))
    return fmaxf(x, 0.0f) + log1pf(expf(-fabsf(x)));
}

__device__ __forceinline__ float wred_sum_f(float v) {
#pragma unroll
    for (int o = 32; o > 0; o >>= 1) v += __shfl_down(v, o, 64);
    return v;
}
__device__ __forceinline__ int wred_sum_i(int v) {
#pragma unroll
    for (int o = 32; o > 0; o >>= 1) v += __shfl_down(v, o, 64);
    return v;
}

__global__ __launch_bounds__(NT, 4) void mbox_row_kernel(
    const float* __restrict__ plocs,   // (B,P,4)
    const float* __restrict__ pscores, // (B,P,3)
    const float* __restrict__ boxes,   // (B,M,4) xyxy
    const int*   __restrict__ labels,  // (B,M)
    const float* __restrict__ priors,  // (P,4) cxcy
    float* __restrict__ out,           // [total, conf, loc, npos x 128]
    unsigned int* __restrict__ g_cnt,  // ws: zeroed counter
    float* __restrict__ g_conf,        // ws
    float* __restrict__ g_loc,         // ws
    int*   __restrict__ g_np)          // ws
{
    __shared__ float s_vals[P_];          // ov_prior
    __shared__ unsigned char s_obj[P_];   // obj_prior
    __shared__ float s_boxes[M_ * 4];
    __shared__ float s_area[M_];
    __shared__ int   s_labels[M_];
    __shared__ int   s_prior_obj[M_];
    __shared__ float s_wv[NW * M_];
    __shared__ int   s_wi[NW * M_];
    __shared__ float s_pf[2 * NW];        // partial sums (conf, loc)
    __shared__ int   s_pi[NW];            // partial counts
    __shared__ float s_scal[2];
    __shared__ int   s_npos;
    __shared__ unsigned int s_u;          // broadcast (bisection mid / threshold)

    const int b = blockIdx.x;
    const int tid = threadIdx.x;
    const int lane = tid & 63;
    const int wid = tid >> 6;

    if (tid < M_ * 4) s_boxes[tid] = boxes[b * M_ * 4 + tid];
    if (tid >= 64 && tid < 64 + M_) s_labels[tid - 64] = labels[b * M_ + (tid - 64)];
    __syncthreads();
    if (tid < M_) {
        float x0 = s_boxes[tid*4+0], y0 = s_boxes[tid*4+1];
        float x1 = s_boxes[tid*4+2], y1 = s_boxes[tid*4+3];
        s_area[tid] = (x1 - x0) * (y1 - y0);
    }
    __syncthreads();

    // ---- Phase A (fused): per-prior best object AND per-thread per-object best prior
    float bo_v[M_];
    int   bo_i[M_];
#pragma unroll
    for (int m = 0; m < M_; ++m) { bo_v[m] = -1.0f; bo_i[m] = 0x7FFFFFFF; }

    for (int p = tid; p < P_; p += NT) {
        float4 pr = ((const float4*)priors)[p];
        float px0 = pr.x - pr.z * 0.5f;
        float py0 = pr.y - pr.w * 0.5f;
        float px1 = pr.x + pr.z * 0.5f;
        float py1 = pr.y + pr.w * 0.5f;
        float parea = pr.z * pr.w;
        float bestv = -1.0f; int besti = 0;
#pragma unroll
        for (int m = 0; m < M_; ++m) {
            float ltx = fmaxf(s_boxes[m*4+0], px0);
            float lty = fmaxf(s_boxes[m*4+1], py0);
            float rbx = fminf(s_boxes[m*4+2], px1);
            float rby = fminf(s_boxes[m*4+3], py1);
            float wx = fmaxf(rbx - ltx, 0.0f);
            float wy = fmaxf(rby - lty, 0.0f);
            float inter = wx * wy;
            float ov = inter * __builtin_amdgcn_rcpf(s_area[m] + parea - inter);
            if (ov > bestv) { bestv = ov; besti = m; }       // first-max over m
            if (ov > bo_v[m]) { bo_v[m] = ov; bo_i[m] = p; } // first-max over p (p ascending)
        }
        s_vals[p] = bestv;
        s_obj[p]  = (unsigned char)besti;
    }

    // ---- Phase B: reduce per-object best prior (wave shuffles, then cross-wave)
#pragma unroll
    for (int m = 0; m < M_; ++m) {
        float v = bo_v[m]; int i = bo_i[m];
#pragma unroll
        for (int o = 32; o > 0; o >>= 1) {
            float v2 = __shfl_down(v, o, 64);
            int   i2 = __shfl_down(i, o, 64);
            if (v2 > v || (v2 == v && i2 < i)) { v = v2; i = i2; }
        }
        if (lane == 0) { s_wv[wid * M_ + m] = v; s_wi[wid * M_ + m] = i; }
    }
    __syncthreads();
    if (tid < M_) {
        float v = s_wv[tid]; int i = s_wi[tid];
#pragma unroll
        for (int w = 1; w < NW; ++w) {
            float v2 = s_wv[w * M_ + tid]; int i2 = s_wi[w * M_ + tid];
            if (v2 > v || (v2 == v && i2 < i)) { v = v2; i = i2; }
        }
        s_prior_obj[tid] = i;
    }
    __syncthreads();

    // ---- Phase C: fixup scatter (serial, last m wins on duplicate priors)
    if (tid == 0) {
        for (int m = 0; m < M_; ++m) {
            int idx = s_prior_obj[m];
            s_obj[idx]  = (unsigned char)m;
            s_vals[idx] = 1.0f;
        }
    }
    __syncthreads();

    // ---- Phase D: labels, BCE, L1 on positives; bce_neg kept in REGISTERS
    float fv[NP9];   // conf_neg values (0 at positives / invalid)
    int   n_pos = 0;
    float conf_pos = 0.0f;
    float loc_sum = 0.0f;
#pragma unroll
    for (int i = 0; i < NP9; ++i) {
        fv[i] = 0.0f;
        int p = tid + i * NT;
        if (p < P_) {
            float ovp = s_vals[p];
            int obj = s_obj[p];
            int lab = (ovp < 0.5f) ? 0 : s_labels[obj];
            const float* sc = pscores + ((size_t)b * P_ + p) * 3;
            float x0 = sc[0], x1 = sc[1], x2 = sc[2];
            float t0 = (lab == 0) ? 1.0f : 0.0f;
            float t1 = (lab == 1 || lab == 3) ? 1.0f : 0.0f;
            float t2 = (lab == 2 || lab == 3) ? 1.0f : 0.0f;
            float bce = (softplusf(x0) - x0*t0) + (softplusf(x1) - x1*t1) + (softplusf(x2) - x2*t2);
            bool pos = lab > 0;
            if (pos) {
                n_pos++;
                conf_pos += bce;
                float4 pr = ((const float4*)priors)[p];
                float bx0 = s_boxes[obj*4+0], by0 = s_boxes[obj*4+1];
                float bx1 = s_boxes[obj*4+2], by1 = s_boxes[obj*4+3];
                float cx = (bx0 + bx1) * 0.5f, cy = (by0 + by1) * 0.5f;
                float w = bx1 - bx0, h = by1 - by0;
                float g0 = (cx - pr.x) / (pr.z * 0.1f);
                float g1 = (cy - pr.y) / (pr.w * 0.1f);
                float g2 = logf(w / pr.z) * 5.0f;
                float g3 = logf(h / pr.w) * 5.0f;
                float4 pl = ((const float4*)plocs)[(size_t)b * P_ + p];
                loc_sum += fabsf(pl.x - g0) + fabsf(pl.y - g1) + fabsf(pl.z - g2) + fabsf(pl.w - g3);
            } else {
                fv[i] = bce;
            }
        }
    }

    // ---- reduce n_pos, conf_pos, loc_sum (wave shuffle + cross-wave)
    {
        float cp = wred_sum_f(conf_pos);
        float ls = wred_sum_f(loc_sum);
        int   np = wred_sum_i(n_pos);
        if (lane == 0) { s_pf[wid] = cp; s_pf[NW + wid] = ls; s_pi[wid] = np; }
    }
    __syncthreads();
    if (tid == 0) {
        float cp = 0.0f, ls = 0.0f; int np = 0;
#pragma unroll
        for (int w = 0; w < NW; ++w) { cp += s_pf[w]; ls += s_pf[NW + w]; np += s_pi[w]; }
        s_scal[0] = cp; s_scal[1] = ls; s_npos = np;
    }
    __syncthreads();
    const int npos_row = s_npos;

    // ---- Phase E: exact top-k sum via 31-step bit-pattern bisection (register values)
    int k = 3 * npos_row;
    if (k > P_) k = P_;
    float hard_sum = 0.0f;
    if (k > 0) {
        long long lo = -1, hi = 0x7F800000LL;   // tid0-owned; invariant cnt(lo)>=k, cnt(hi)<k
        for (int it = 0; it < 31; ++it) {
            if (tid == 0) s_u = (unsigned int)((lo + hi) >> 1);
            __syncthreads();
            unsigned int mid = s_u;
            int c = 0;
#pragma unroll
            for (int i = 0; i < NP9; ++i) c += (__float_as_uint(fv[i]) > mid) ? 1 : 0;
            c = wred_sum_i(c);
            if (lane == 0) s_pi[wid] = c;
            __syncthreads();
            if (tid == 0) {
                int cnt = 0;
#pragma unroll
                for (int w = 0; w < NW; ++w) cnt += s_pi[w];
                long long m2 = (lo + hi) >> 1;
                if (cnt < k) hi = m2; else lo = m2;
            }
        }
        if (tid == 0) s_u = (unsigned int)hi;   // = k-th largest bit pattern, exact
        __syncthreads();
        unsigned int tbits = s_u;
        float tval = __uint_as_float(tbits);
        float lsum = 0.0f; int lcnt = 0;
#pragma unroll
        for (int i = 0; i < NP9; ++i) {
            if (__float_as_uint(fv[i]) > tbits) { lsum += fv[i]; lcnt++; }
        }
        lsum = wred_sum_f(lsum);
        lcnt = wred_sum_i(lcnt);
        if (lane == 0) { s_pf[wid] = lsum; s_pi[wid] = lcnt; }
        __syncthreads();
        if (tid == 0) {
            float sv = 0.0f; int sc2 = 0;
#pragma unroll
            for (int w = 0; w < NW; ++w) { sv += s_pf[w]; sc2 += s_pi[w]; }
            hard_sum = sv + (float)(k - sc2) * tval;
        }
    }

    // ---- finalize: per-row output + last-block global reduction
    if (tid == 0) {
        float conf_row = s_scal[0] + hard_sum;
        float loc_row  = s_scal[1];
        out[3 + b] = (float)npos_row;
        atomicAdd(g_conf, conf_row);
        atomicAdd(g_loc,  loc_row);
        atomicAdd(g_np,   npos_row);
        __threadfence();
        unsigned int done = atomicAdd(g_cnt, 1u);
        if (done == B_ - 1) {
            float ct = atomicAdd(g_conf, 0.0f);  // read at coherent point
            float lt = atomicAdd(g_loc,  0.0f);
            int   np = atomicAdd(g_np,   0);
            float npt = (float)np;
            float conf_loss = ct / (1e-10f + npt);
            float loc_loss = (np > 0) ? lt / (4.0f * fmaxf(npt, 1.0f)) : 0.0f;
            out[0] = conf_loss + loc_loss;   // ALPHA = 1
            out[1] = conf_loss;
            out[2] = loc_loss;
        }
    }
}

extern "C" void kernel_launch(void* const* d_in, const int* in_sizes, int n_in,
                              void* d_out, int out_size, void* d_ws, size_t ws_size,
                              hipStream_t stream) {
    const float* plocs   = (const float*)d_in[0];  // (B,P,4)
    const float* pscores = (const float*)d_in[1];  // (B,P,3)
    const float* boxes   = (const float*)d_in[2];  // (B,M,4)
    const int*   labels  = (const int*)  d_in[3];  // (B,M)
    const float* priors  = (const float*)d_in[4];  // (P,4)
    float* out = (float*)d_out;

    unsigned int* g_cnt  = (unsigned int*)d_ws;
    float*        g_conf = (float*)((char*)d_ws + 4);
    float*        g_loc  = (float*)((char*)d_ws + 8);
    int*          g_np   = (int*)  ((char*)d_ws + 12);

    hipMemsetAsync(d_ws, 0, 16, stream);   // zero counter + accumulators
    mbox_row_kernel<<<B_, NT, 0, stream>>>(plocs, pscores, boxes, labels, priors,
                                           out, g_cnt, g_conf, g_loc, g_np);
}

// Round 5
// 172.406 us; speedup vs baseline: 1.3424x; 1.0124x over previous
//
#include <hip/hip_runtime.h>
#include <cstdint>
#include <cmath>

#define B_ 128
#define P_ 8732
#define M_ 16
#define NT 1024
#define NW (NT / 64)
#define NP9 9   // ceil(P_/NT)

__device__ __forceinline__ float softplusf(float x) {
    // logaddexp(0, x) = max(x,0) + log1p(exp(-|x|))
    return fmaxf(x, 0.0f) + log1pf(expf(-fabsf(x)));
}

__device__ __forceinline__ float wred_sum_f(float v) {
#pragma unroll
    for (int o = 32; o > 0; o >>= 1) v += __shfl_down(v, o, 64);
    return v;
}
__device__ __forceinline__ int wred_sum_i(int v) {
#pragma unroll
    for (int o = 32; o > 0; o >>= 1) v += __shfl_down(v, o, 64);
    return v;
}

__global__ __launch_bounds__(NT)
__attribute__((amdgpu_waves_per_eu(4)))   // min 4 waves/EU -> VGPR cap 128, no spills
void mbox_row_kernel(
    const float* __restrict__ plocs,   // (B,P,4)
    const float* __restrict__ pscores, // (B,P,3)
    const float* __restrict__ boxes,   // (B,M,4) xyxy
    const int*   __restrict__ labels,  // (B,M)
    const float* __restrict__ priors,  // (P,4) cxcy
    float* __restrict__ out,           // [total, conf, loc, npos x 128]
    unsigned int* __restrict__ g_cnt,  // ws: zeroed counter
    float* __restrict__ g_conf,        // ws
    float* __restrict__ g_loc,         // ws
    int*   __restrict__ g_np)          // ws
{
    __shared__ float s_vals[P_];          // ov_prior
    __shared__ unsigned char s_obj[P_];   // obj_prior
    __shared__ float s_boxes[M_ * 4];
    __shared__ float s_area[M_];
    __shared__ int   s_labels[M_];
    __shared__ int   s_prior_obj[M_];
    __shared__ float s_wv[NW * M_];
    __shared__ int   s_wi[NW * M_];
    __shared__ float s_pf[2 * NW];        // partial sums (conf, loc)
    __shared__ int   s_pi[NW];            // partial counts
    __shared__ int   s_cnt2[2][NW];       // bisection partial counts, parity-buffered
    __shared__ float s_scal[2];
    __shared__ int   s_npos;

    const int b = blockIdx.x;
    const int tid = threadIdx.x;
    const int lane = tid & 63;
    const int wid = tid >> 6;

    if (tid < M_ * 4) s_boxes[tid] = boxes[b * M_ * 4 + tid];
    if (tid >= 64 && tid < 64 + M_) s_labels[tid - 64] = labels[b * M_ + (tid - 64)];
    __syncthreads();
    if (tid < M_) {
        float x0 = s_boxes[tid*4+0], y0 = s_boxes[tid*4+1];
        float x1 = s_boxes[tid*4+2], y1 = s_boxes[tid*4+3];
        s_area[tid] = (x1 - x0) * (y1 - y0);
    }
    __syncthreads();

    // ---- Phase A (fused): per-prior best object AND per-thread per-object best prior
    float bo_v[M_];
    int   bo_i[M_];
#pragma unroll
    for (int m = 0; m < M_; ++m) { bo_v[m] = -1.0f; bo_i[m] = 0x7FFFFFFF; }

    for (int p = tid; p < P_; p += NT) {
        float4 pr = ((const float4*)priors)[p];
        float px0 = pr.x - pr.z * 0.5f;
        float py0 = pr.y - pr.w * 0.5f;
        float px1 = pr.x + pr.z * 0.5f;
        float py1 = pr.y + pr.w * 0.5f;
        float parea = pr.z * pr.w;
        float bestv = -1.0f; int besti = 0;
#pragma unroll
        for (int m = 0; m < M_; ++m) {
            float ltx = fmaxf(s_boxes[m*4+0], px0);
            float lty = fmaxf(s_boxes[m*4+1], py0);
            float rbx = fminf(s_boxes[m*4+2], px1);
            float rby = fminf(s_boxes[m*4+3], py1);
            float wx = fmaxf(rbx - ltx, 0.0f);
            float wy = fmaxf(rby - lty, 0.0f);
            float inter = wx * wy;
            float ov = inter * __builtin_amdgcn_rcpf(s_area[m] + parea - inter);
            if (ov > bestv) { bestv = ov; besti = m; }       // first-max over m
            if (ov > bo_v[m]) { bo_v[m] = ov; bo_i[m] = p; } // first-max over p (p ascending)
        }
        s_vals[p] = bestv;
        s_obj[p]  = (unsigned char)besti;
    }

    // ---- Phase B: reduce per-object best prior (wave shuffles, then cross-wave)
#pragma unroll
    for (int m = 0; m < M_; ++m) {
        float v = bo_v[m]; int i = bo_i[m];
#pragma unroll
        for (int o = 32; o > 0; o >>= 1) {
            float v2 = __shfl_down(v, o, 64);
            int   i2 = __shfl_down(i, o, 64);
            if (v2 > v || (v2 == v && i2 < i)) { v = v2; i = i2; }
        }
        if (lane == 0) { s_wv[wid * M_ + m] = v; s_wi[wid * M_ + m] = i; }
    }
    __syncthreads();
    if (tid < M_) {
        float v = s_wv[tid]; int i = s_wi[tid];
#pragma unroll
        for (int w = 1; w < NW; ++w) {
            float v2 = s_wv[w * M_ + tid]; int i2 = s_wi[w * M_ + tid];
            if (v2 > v || (v2 == v && i2 < i)) { v = v2; i = i2; }
        }
        s_prior_obj[tid] = i;
    }
    __syncthreads();

    // ---- Phase C: fixup scatter (serial, last m wins on duplicate priors)
    if (tid == 0) {
        for (int m = 0; m < M_; ++m) {
            int idx = s_prior_obj[m];
            s_obj[idx]  = (unsigned char)m;
            s_vals[idx] = 1.0f;
        }
    }
    __syncthreads();

    // ---- Phase D: labels, BCE, L1 on positives; bce_neg kept in REGISTERS
    float fv[NP9];   // conf_neg values (0 at positives / invalid)
    int   n_pos = 0;
    float conf_pos = 0.0f;
    float loc_sum = 0.0f;
#pragma unroll
    for (int i = 0; i < NP9; ++i) {
        fv[i] = 0.0f;
        int p = tid + i * NT;
        if (p < P_) {
            float ovp = s_vals[p];
            int obj = s_obj[p];
            int lab = (ovp < 0.5f) ? 0 : s_labels[obj];
            const float* sc = pscores + ((size_t)b * P_ + p) * 3;
            float x0 = sc[0], x1 = sc[1], x2 = sc[2];
            float t0 = (lab == 0) ? 1.0f : 0.0f;
            float t1 = (lab == 1 || lab == 3) ? 1.0f : 0.0f;
            float t2 = (lab == 2 || lab == 3) ? 1.0f : 0.0f;
            float bce = (softplusf(x0) - x0*t0) + (softplusf(x1) - x1*t1) + (softplusf(x2) - x2*t2);
            bool pos = lab > 0;
            if (pos) {
                n_pos++;
                conf_pos += bce;
                float4 pr = ((const float4*)priors)[p];
                float bx0 = s_boxes[obj*4+0], by0 = s_boxes[obj*4+1];
                float bx1 = s_boxes[obj*4+2], by1 = s_boxes[obj*4+3];
                float cx = (bx0 + bx1) * 0.5f, cy = (by0 + by1) * 0.5f;
                float w = bx1 - bx0, h = by1 - by0;
                float g0 = (cx - pr.x) / (pr.z * 0.1f);
                float g1 = (cy - pr.y) / (pr.w * 0.1f);
                float g2 = logf(w / pr.z) * 5.0f;
                float g3 = logf(h / pr.w) * 5.0f;
                float4 pl = ((const float4*)plocs)[(size_t)b * P_ + p];
                loc_sum += fabsf(pl.x - g0) + fabsf(pl.y - g1) + fabsf(pl.z - g2) + fabsf(pl.w - g3);
            } else {
                fv[i] = bce;
            }
        }
    }

    // ---- reduce n_pos, conf_pos, loc_sum (wave shuffle + cross-wave)
    {
        float cp = wred_sum_f(conf_pos);
        float ls = wred_sum_f(loc_sum);
        int   np = wred_sum_i(n_pos);
        if (lane == 0) { s_pf[wid] = cp; s_pf[NW + wid] = ls; s_pi[wid] = np; }
    }
    __syncthreads();
    if (tid == 0) {
        float cp = 0.0f, ls = 0.0f; int np = 0;
#pragma unroll
        for (int w = 0; w < NW; ++w) { cp += s_pf[w]; ls += s_pf[NW + w]; np += s_pi[w]; }
        s_scal[0] = cp; s_scal[1] = ls; s_npos = np;
    }
    __syncthreads();
    const int npos_row = s_npos;

    // ---- Phase E: exact top-k via bit-pattern bisection; state replicated per
    //      thread (deterministic), parity-buffered partials -> 1 barrier/iter.
    int k = 3 * npos_row;
    if (k > P_) k = P_;
    float hard_sum = 0.0f;
    if (k > 0) {
        long long lo = -1, hi = 0x7F800000LL;   // invariant: cnt(lo)>=k, cnt(hi)<k
        for (int it = 0; it < 31; ++it) {
            unsigned int mid = (unsigned int)((lo + hi) >> 1);
            int c = 0;
#pragma unroll
            for (int i = 0; i < NP9; ++i) c += (__float_as_uint(fv[i]) > mid) ? 1 : 0;
            c = wred_sum_i(c);
            if (lane == 0) s_cnt2[it & 1][wid] = c;
            __syncthreads();
            int cnt = 0;
#pragma unroll
            for (int w = 0; w < NW; ++w) cnt += s_cnt2[it & 1][w];
            if (cnt < k) hi = (lo + hi) >> 1; else lo = (lo + hi) >> 1;
        }
        unsigned int tbits = (unsigned int)hi;   // k-th largest bit pattern, exact
        float tval = __uint_as_float(tbits);
        float lsum = 0.0f; int lcnt = 0;
#pragma unroll
        for (int i = 0; i < NP9; ++i) {
            if (__float_as_uint(fv[i]) > tbits) { lsum += fv[i]; lcnt++; }
        }
        lsum = wred_sum_f(lsum);
        lcnt = wred_sum_i(lcnt);
        if (lane == 0) { s_pf[wid] = lsum; s_pi[wid] = lcnt; }
        __syncthreads();
        if (tid == 0) {
            float sv = 0.0f; int sc2 = 0;
#pragma unroll
            for (int w = 0; w < NW; ++w) { sv += s_pf[w]; sc2 += s_pi[w]; }
            hard_sum = sv + (float)(k - sc2) * tval;
        }
    }

    // ---- finalize: per-row output + last-block global reduction
    if (tid == 0) {
        float conf_row = s_scal[0] + hard_sum;
        float loc_row  = s_scal[1];
        out[3 + b] = (float)npos_row;
        atomicAdd(g_conf, conf_row);
        atomicAdd(g_loc,  loc_row);
        atomicAdd(g_np,   npos_row);
        __threadfence();
        unsigned int done = atomicAdd(g_cnt, 1u);
        if (done == B_ - 1) {
            float ct = atomicAdd(g_conf, 0.0f);  // read at coherent point
            float lt = atomicAdd(g_loc,  0.0f);
            int   np = atomicAdd(g_np,   0);
            float npt = (float)np;
            float conf_loss = ct / (1e-10f + npt);
            float loc_loss = (np > 0) ? lt / (4.0f * fmaxf(npt, 1.0f)) : 0.0f;
            out[0] = conf_loss + loc_loss;   // ALPHA = 1
            out[1] = conf_loss;
            out[2] = loc_loss;
        }
    }
}

extern "C" void kernel_launch(void* const* d_in, const int* in_sizes, int n_in,
                              void* d_out, int out_size, void* d_ws, size_t ws_size,
                              hipStream_t stream) {
    const float* plocs   = (const float*)d_in[0];  // (B,P,4)
    const float* pscores = (const float*)d_in[1];  // (B,P,3)
    const float* boxes   = (const float*)d_in[2];  // (B,M,4)
    const int*   labels  = (const int*)  d_in[3];  // (B,M)
    const float* priors  = (const float*)d_in[4];  // (P,4)
    float* out = (float*)d_out;

    unsigned int* g_cnt  = (unsigned int*)d_ws;
    float*        g_conf = (float*)((char*)d_ws + 4);
    float*        g_loc  = (float*)((char*)d_ws + 8);
    int*          g_np   = (int*)  ((char*)d_ws + 12);

    hipMemsetAsync(d_ws, 0, 16, stream);   // zero counter + accumulators
    mbox_row_kernel<<<B_, NT, 0, stream>>>(plocs, pscores, boxes, labels, priors,
                                           out, g_cnt, g_conf, g_loc, g_np);
}